// Round 9
// baseline (338.027 us; speedup 1.0000x reference)
//
#include <hip/hip_runtime.h>
#include <stdint.h>

#define R_ 64
#define C_ 512
#define E_ 768
#define H_ 12
#define D_ 64
#define M_TOT (R_*C_)   // 32768

using short4v = __attribute__((ext_vector_type(4))) short;
using short8  = __attribute__((ext_vector_type(8))) short;
using f32x4   = __attribute__((ext_vector_type(4))) float;
using floatv4 = __attribute__((ext_vector_type(4))) float;

#define MFMA16(a,b,c) __builtin_amdgcn_mfma_f32_16x16x32_bf16(a,b,c,0,0,0)

__device__ __forceinline__ short f2bf(float f){
  union { float f; unsigned u; } c; c.f = f;
  unsigned u = c.u;
  u += 0x7fffu + ((u >> 16) & 1u);   // RNE
  return (short)(u >> 16);
}

// async global->LDS, 16B per lane. LDS dest is wave-uniform base; HW adds lane*16.
__device__ __forceinline__ void gload16(const void* g, void* lds){
  __builtin_amdgcn_global_load_lds(
      (const __attribute__((address_space(1))) void*)(uintptr_t)g,
      (__attribute__((address_space(3))) void*)(uint32_t)(uintptr_t)lds,
      16, 0, 0);
}

struct Lin {
  const short* p; int ld;
  __device__ __forceinline__ const short* at(int r, int c) const {
    return p + (long)r * ld + c;
  }
};
// oproj A operand: ctx stored as ctx_t[h][i][r*64+d]; m = r*512+i, k = h*64+d
struct CtxMap {
  const short* p;
  __device__ __forceinline__ const short* at(int m, int k) const {
    return p + ((long)((k >> 6) * 512 + (m & 511))) * 4096 + ((m >> 9) << 6) + (k & 63);
  }
};

// ---------------------------------------------------------------------------
// m201-geometry GEMM core. BM=256, BN=256, BK=64. 512 threads = 8 waves
// (2M x 4N); per-wave output 128x64 = acc[8][4] frags (MFMA:ds_read = 2.67).
// LDS 128 KB: A = 2 dbuf x 2 k-half x (256 rows x 32 cols bf16, 16 KB),
// B same at +32768 shorts. Half-tile staged per phase (2 gloads/thread).
// Swizzle (HW-verified involution): rows pair into 128B lines; 16B slot
// slot = ((row&1)*4 + g) ^ (line&7); stage inverts it on the global address,
// LDS dest stays linear (rule #21 both-sides).
// Sync: vmcnt(4)+barrier at mid-tile and tile-end (8 loads outstanding,
// wait drains oldest 2 half-tiles). Never vmcnt(0) until the tail.
// Race-freedom: stages during tile t write buf (t+1)&1, which was last read
// in tile t-1; those reads retired before t-1's end barrier (MFMA data dep),
// and t's stages issue only after that barrier.
// ---------------------------------------------------------------------------
template<class AT, class BT>
__device__ __forceinline__ void gemm256(
    const AT& A, const BT& B, int m0, int n0, int K,
    short* smem, f32x4 (&acc)[8][4])
{
  const int t = threadIdx.x, l = t & 63, w = t >> 6;
  const int wm = w >> 2, wn = w & 3;

  auto stageA = [&](int kcol, short* dst){
    #pragma unroll
    for (int u = 0; u < 2; ++u){
      const int s = (w*2 + u)*64 + l;
      const int line = s >> 3, slot = s & 7;
      const int v = slot ^ (line & 7);
      const int row = line*2 + (v >> 2);
      gload16(A.at(m0 + row, kcol + (v & 3)*8), dst + (w*2 + u)*512);
    }
  };
  auto stageB = [&](int kcol, short* dst){
    #pragma unroll
    for (int u = 0; u < 2; ++u){
      const int s = (w*2 + u)*64 + l;
      const int line = s >> 3, slot = s & 7;
      const int v = slot ^ (line & 7);
      const int row = line*2 + (v >> 2);
      gload16(B.at(n0 + row, kcol + (v & 3)*8), dst + (w*2 + u)*512);
    }
  };
  auto rdf = [&](const short* half, int row0)->short8{
    const int r = row0 + (l & 15);
    const int line = r >> 1;
    const int slot = ((r & 1)*4 + (l >> 4)) ^ (line & 7);
    return *(const short8*)(half + line*64 + slot*8);
  };

  short* As[2] = { smem,         smem + 16384 };   // [buf]: half0; half1 at +8192
  short* Bs[2] = { smem + 32768, smem + 49152 };

  const int NT = K >> 6;
  stageA(0,  As[0]);        stageB(0,  Bs[0]);
  stageA(32, As[0] + 8192); stageB(32, Bs[0] + 8192);
  asm volatile("s_waitcnt vmcnt(4)" ::: "memory");
  __builtin_amdgcn_s_barrier();
  asm volatile("" ::: "memory");

  for (int kt = 0; kt < NT; ++kt){
    const int b = kt & 1, nb = b ^ 1;
    const bool pf = (kt + 1 < NT);
    const int kc = (kt + 1) * 64;
    const short* Ah0 = As[b];
    const short* Ah1 = As[b] + 8192;
    const short* Bh0 = Bs[b];
    const short* Bh1 = Bs[b] + 8192;
    short8 af[4], bf[4];

    // p0: ks0, m0-3 x n0-3 ; stage Ak0(t+1)
    #pragma unroll
    for (int m = 0; m < 4; ++m) af[m] = rdf(Ah0, wm*128 + m*16);
    #pragma unroll
    for (int n = 0; n < 4; ++n) bf[n] = rdf(Bh0, wn*64 + n*16);
    if (pf) stageA(kc, As[nb]);
    __builtin_amdgcn_s_setprio(1);
    #pragma unroll
    for (int m = 0; m < 4; ++m)
      #pragma unroll
      for (int n = 0; n < 4; ++n)
        acc[m][n] = MFMA16(af[m], bf[n], acc[m][n]);
    __builtin_amdgcn_s_setprio(0);

    // p1: ks0, m4-7 ; stage Bk0(t+1)
    #pragma unroll
    for (int m = 0; m < 4; ++m) af[m] = rdf(Ah0, wm*128 + (m+4)*16);
    if (pf) stageB(kc, Bs[nb]);
    __builtin_amdgcn_s_setprio(1);
    #pragma unroll
    for (int m = 0; m < 4; ++m)
      #pragma unroll
      for (int n = 0; n < 4; ++n)
        acc[m+4][n] = MFMA16(af[m], bf[n], acc[m+4][n]);
    __builtin_amdgcn_s_setprio(0);

    if (pf) asm volatile("s_waitcnt vmcnt(4)" ::: "memory");
    else    asm volatile("s_waitcnt vmcnt(0)" ::: "memory");
    __builtin_amdgcn_s_barrier();
    asm volatile("" ::: "memory");

    // p2: ks1, m0-3 x n0-3 ; stage Ak1(t+1)
    #pragma unroll
    for (int m = 0; m < 4; ++m) af[m] = rdf(Ah1, wm*128 + m*16);
    #pragma unroll
    for (int n = 0; n < 4; ++n) bf[n] = rdf(Bh1, wn*64 + n*16);
    if (pf) stageA(kc + 32, As[nb] + 8192);
    __builtin_amdgcn_s_setprio(1);
    #pragma unroll
    for (int m = 0; m < 4; ++m)
      #pragma unroll
      for (int n = 0; n < 4; ++n)
        acc[m][n] = MFMA16(af[m], bf[n], acc[m][n]);
    __builtin_amdgcn_s_setprio(0);

    // p3: ks1, m4-7 ; stage Bk1(t+1)
    #pragma unroll
    for (int m = 0; m < 4; ++m) af[m] = rdf(Ah1, wm*128 + (m+4)*16);
    if (pf) stageB(kc + 32, Bs[nb] + 8192);
    __builtin_amdgcn_s_setprio(1);
    #pragma unroll
    for (int m = 0; m < 4; ++m)
      #pragma unroll
      for (int n = 0; n < 4; ++n)
        acc[m+4][n] = MFMA16(af[m], bf[n], acc[m+4][n]);
    __builtin_amdgcn_s_setprio(0);

    if (pf) asm volatile("s_waitcnt vmcnt(4)" ::: "memory");
    else    asm volatile("s_waitcnt vmcnt(0)" ::: "memory");
    __builtin_amdgcn_s_barrier();
    asm volatile("" ::: "memory");
  }
}

#define ACC_INIT8(acc) \
  _Pragma("unroll") for (int m_=0;m_<8;m_++) _Pragma("unroll") for (int n_=0;n_<4;n_++) \
    acc[m_][n_] = (f32x4){0.f,0.f,0.f,0.f};

// ---------------------------------------------------------------------------
__global__ __launch_bounds__(256) void cvt_k(
    const float* __restrict__ in, short* __restrict__ out, int n8, float scale)
{
  int i = blockIdx.x * blockDim.x + threadIdx.x;
  const int stride = gridDim.x * blockDim.x;
  for (; i < n8; i += stride){
    floatv4 a = *(const floatv4*)(in + (long)i*8);
    floatv4 b = *(const floatv4*)(in + (long)i*8 + 4);
    short8 s;
    #pragma unroll
    for (int j = 0; j < 4; ++j){ s[j] = f2bf(a[j]*scale); s[4+j] = f2bf(b[j]*scale); }
    *(short8*)(out + (long)i*8) = s;
  }
}

__global__ __launch_bounds__(256) void cvt_w_k(
    const float* __restrict__ Wq, const float* __restrict__ Wk,
    const float* __restrict__ Wv, const float* __restrict__ Wo,
    short* __restrict__ out)
{
  const int i = blockIdx.x * blockDim.x + threadIdx.x;
  const int wsel = i / 73728, j = i - wsel * 73728;
  const float* src = (wsel == 0) ? Wq : (wsel == 1) ? Wk : (wsel == 2) ? Wv : Wo;
  const float scale = (wsel == 0) ? 0.015625f : 1.0f;
  floatv4 a = *(const floatv4*)(src + (long)j*8);
  floatv4 b = *(const floatv4*)(src + (long)j*8 + 4);
  short8 s;
  #pragma unroll
  for (int q = 0; q < 4; ++q){ s[q] = f2bf(a[q]*scale); s[4+q] = f2bf(b[q]*scale); }
  *(short8*)(out + (long)i*8) = s;
}

// ---------------------------------------------------------------------------
// Projection: grid (128 mt, 3 nt, 3 which). q->qt[h][i][rd] (scaled),
// k->kt, v->vtt[h][rd][j] via LDS-bounce transpose.
// ---------------------------------------------------------------------------
__global__ __launch_bounds__(512, 2) void proj_k(
    const short* __restrict__ xb, const short* __restrict__ wb,
    const float* __restrict__ bq, const float* __restrict__ bk, const float* __restrict__ bv,
    short* __restrict__ qt, short* __restrict__ kt, short* __restrict__ vtt)
{
  __shared__ short smem[65536];
  const int m0 = blockIdx.x * 256, n0 = blockIdx.y * 256;
  const int which = blockIdx.z;

  f32x4 acc[8][4]; ACC_INIT8(acc);
  Lin A{xb, E_};
  Lin B{wb + (long)which * E_ * E_, E_};
  gemm256(A, B, m0, n0, E_, smem, acc);

  const int t = threadIdx.x, l = t & 63, w = t >> 6;
  const int rb = (w >> 2) * 128, cb = (w & 3) * 64;
  const int r = m0 >> 9, i0 = m0 & 511;

  if (which <= 1){
    const float* bias = (which == 0) ? bq : bk;
    short* outp = (which == 0) ? qt : kt;
    const float sc = (which == 0) ? 0.015625f : 1.0f;
    #pragma unroll
    for (int n = 0; n < 4; ++n){
      const int gc = n0 + cb + n*16 + (l & 15);
      const float bb = bias[gc] * sc;
      const int h = gc >> 6, d = gc & 63;
      #pragma unroll
      for (int m = 0; m < 8; ++m){
        #pragma unroll
        for (int rg = 0; rg < 4; ++rg){
          const int gm = m0 + rb + m*16 + (l >> 4)*4 + rg;
          const int i = gm & 511;
          outp[((long)(h*512 + i))*4096 + r*64 + d] = f2bf(acc[m][n][rg] + bb);
        }
      }
    }
  } else {
    // v: bounce [gc 0..255][pos 0..255] (512B rows, 16B-chunk XOR gc&31)
    char* lb = (char*)smem;
    #pragma unroll
    for (int n = 0; n < 4; ++n){
      const int gcl = cb + n*16 + (l & 15);
      const float bb = bv[n0 + gcl];
      #pragma unroll
      for (int m = 0; m < 8; ++m){
        const int pos = rb + m*16 + (l >> 4)*4;
        short4v s;
        #pragma unroll
        for (int rg = 0; rg < 4; ++rg) s[rg] = f2bf(acc[m][n][rg] + bb);
        const int byteoff = gcl*512 + ((((pos >> 3) ^ (gcl & 31))) << 4) + (pos & 7)*2;
        *(short4v*)(lb + byteoff) = s;
      }
    }
    __builtin_amdgcn_s_barrier();
    asm volatile("" ::: "memory");
    const int gcl = t >> 1, cc = t & 1;
    const int gd = n0 + gcl;
    const int h = gd >> 6, dd = gd & 63;
    short* dst = vtt + ((long)h*4096 + r*64 + dd)*512 + i0 + cc*128;
    #pragma unroll
    for (int j = 0; j < 16; ++j){
      const int c = cc*16 + j;
      short8 vv = *(const short8*)(lb + gcl*512 + ((c ^ (gcl & 31)) << 4));
      *(short8*)(dst + j*8) = vv;
    }
  }
}

// ---------------------------------------------------------------------------
// Logits split-K x4: grid (2,2,48), z = h*4+s, K-slice 1024. f32 partials.
// ---------------------------------------------------------------------------
__global__ __launch_bounds__(512, 2) void logits_k(
    const short* __restrict__ qt, const short* __restrict__ kt,
    float* __restrict__ P0, float* __restrict__ P1,
    float* __restrict__ P2, float* __restrict__ P3)
{
  __shared__ short smem[65536];
  const int m0 = blockIdx.x * 256, n0 = blockIdx.y * 256;
  const int h = blockIdx.z >> 2, s = blockIdx.z & 3;

  f32x4 acc[8][4]; ACC_INIT8(acc);
  Lin A{qt + (long)h * C_ * 4096 + s*1024, 4096};
  Lin B{kt + (long)h * C_ * 4096 + s*1024, 4096};
  gemm256(A, B, m0, n0, 1024, smem, acc);

  float* Ps = (s == 0) ? P0 : (s == 1) ? P1 : (s == 2) ? P2 : P3;
  float* Sh = Ps + (long)h * C_ * C_;
  const int t = threadIdx.x, l = t & 63, w = t >> 6;
  const int rb = (w >> 2) * 128, cb = (w & 3) * 64;
  #pragma unroll
  for (int m = 0; m < 8; ++m){
    #pragma unroll
    for (int n = 0; n < 4; ++n){
      #pragma unroll
      for (int rg = 0; rg < 4; ++rg){
        const int gi = m0 + rb + m*16 + (l >> 4)*4 + rg;
        const int gj = n0 + cb + n*16 + (l & 15);
        Sh[(long)gi * C_ + gj] = acc[m][n][rg];
      }
    }
  }
}

// ---------------------------------------------------------------------------
__global__ __launch_bounds__(256) void softmax4_k(
    const float* __restrict__ P0, const float* __restrict__ P1,
    const float* __restrict__ P2, const float* __restrict__ P3,
    float* __restrict__ probs, short* __restrict__ Pbf)
{
  const int row = blockIdx.x;       // h*512 + i
  const int i = row & 511;
  const long base = (long)row * C_;
  const int t = threadIdx.x, lane = t & 63, wid = t >> 6;
  __shared__ float red[4];

  float v0 = P0[base+t]     + P1[base+t]     + P2[base+t]     + P3[base+t];
  float v1 = P0[base+t+256] + P1[base+t+256] + P2[base+t+256] + P3[base+t+256];
  if (t == i)       v0 = -1e9f;
  if (t + 256 == i) v1 = -1e9f;

  float mx = fmaxf(v0, v1);
  #pragma unroll
  for (int m = 1; m < 64; m <<= 1) mx = fmaxf(mx, __shfl_xor(mx, m, 64));
  if (lane == 0) red[wid] = mx;
  __syncthreads();
  mx = fmaxf(fmaxf(red[0], red[1]), fmaxf(red[2], red[3]));
  __syncthreads();

  float e0 = __expf(v0 - mx), e1 = __expf(v1 - mx);
  float ssum = e0 + e1;
  #pragma unroll
  for (int m = 1; m < 64; m <<= 1) ssum += __shfl_xor(ssum, m, 64);
  if (lane == 0) red[wid] = ssum;
  __syncthreads();
  const float inv = 1.0f / (red[0] + red[1] + red[2] + red[3]);

  const float p0 = e0 * inv, p1 = e1 * inv;
  probs[base + t] = p0; probs[base + t + 256] = p1;
  Pbf[base + t] = f2bf(p0);
  Pbf[base + t + 256] = f2bf(p1);
}

// ---------------------------------------------------------------------------
// Context: grid (2,16,12). ctx_t[h][i][rd] = P_h @ Vtt_h^T (NT, K=512).
// ---------------------------------------------------------------------------
__global__ __launch_bounds__(512, 2) void ctx_k(
    const short* __restrict__ pb, const short* __restrict__ vtt, short* __restrict__ ctx_t)
{
  __shared__ short smem[65536];
  const int m0 = blockIdx.x * 256, n0 = blockIdx.y * 256;
  const int h = blockIdx.z;

  f32x4 acc[8][4]; ACC_INIT8(acc);
  Lin A{pb + (long)h * C_ * C_, C_};
  Lin B{vtt + (long)h * 4096 * C_, C_};
  gemm256(A, B, m0, n0, C_, smem, acc);

  short* outh = ctx_t + (long)h * C_ * 4096;
  const int t = threadIdx.x, l = t & 63, w = t >> 6;
  const int rb = (w >> 2) * 128, cb = (w & 3) * 64;
  #pragma unroll
  for (int m = 0; m < 8; ++m){
    #pragma unroll
    for (int n = 0; n < 4; ++n){
      #pragma unroll
      for (int rg = 0; rg < 4; ++rg){
        const int gi = m0 + rb + m*16 + (l >> 4)*4 + rg;
        const int gn = n0 + cb + n*16 + (l & 15);
        outh[(long)gi * 4096 + gn] = f2bf(acc[m][n][rg]);
      }
    }
  }
}

// ---------------------------------------------------------------------------
// Output projection: grid (128, 3). out = ctx @ Wo^T + bo, f32.
// ---------------------------------------------------------------------------
__global__ __launch_bounds__(512, 2) void oproj_k(
    const short* __restrict__ ctx_t, const short* __restrict__ wo,
    const float* __restrict__ bo, float* __restrict__ out)
{
  __shared__ short smem[65536];
  const int m0 = blockIdx.x * 256, n0 = blockIdx.y * 256;

  f32x4 acc[8][4]; ACC_INIT8(acc);
  CtxMap A{ctx_t};
  Lin B{wo, E_};
  gemm256(A, B, m0, n0, E_, smem, acc);

  const int t = threadIdx.x, l = t & 63, w = t >> 6;
  const int rb = (w >> 2) * 128, cb = (w & 3) * 64;
  #pragma unroll
  for (int n = 0; n < 4; ++n){
    const int gc = n0 + cb + n*16 + (l & 15);
    const float bb = bo[gc];
    #pragma unroll
    for (int m = 0; m < 8; ++m){
      #pragma unroll
      for (int rg = 0; rg < 4; ++rg){
        const int gm = m0 + rb + m*16 + (l >> 4)*4 + rg;
        out[(long)gm * E_ + gc] = acc[m][n][rg] + bb;
      }
    }
  }
}

// ---------------------------------------------------------------------------
extern "C" void kernel_launch(void* const* d_in, const int* in_sizes, int n_in,
                              void* d_out, int out_size, void* d_ws, size_t ws_size,
                              hipStream_t stream)
{
  const float* x  = (const float*)d_in[0];
  const float* Wq = (const float*)d_in[2];
  const float* bq = (const float*)d_in[3];
  const float* Wk = (const float*)d_in[4];
  const float* bk = (const float*)d_in[5];
  const float* Wv = (const float*)d_in[6];
  const float* bv = (const float*)d_in[7];
  const float* Wo = (const float*)d_in[8];
  const float* bo = (const float*)d_in[9];
  const float* l  = (const float*)d_in[10];

  float* out   = (float*)d_out;                          // [32768][768] = 25,165,824 f
  float* probs = out + (size_t)M_TOT * E_;               // [12][512][512] f32
  float* lout  = probs + (size_t)H_ * C_ * C_;           // [12]

  // out-region scratch (dead until oproj): 4 logits partials + vtt (exact fit)
  float* P0  = out;                                      // 3,145,728 f
  float* P1  = out + 3145728;
  short* vtt = (short*)(out + 6291456);                  // 25,165,824 shorts
  float* P2  = out + 18874368;
  float* P3  = out + 22020096;

  short* ws_s = (short*)d_ws;
  const size_t SLOT = (size_t)M_TOT * E_;                // 25,165,824 elems
  short* s0 = ws_s;                // xb
  short* s1 = ws_s + SLOT;         // qt -> ctx_t
  short* s2 = ws_s + 2*SLOT;       // kt -> pb
  short* wb = ws_s + 3*SLOT;       // 4 x 589824 bf16 weights

  hipMemcpyAsync(lout, l, H_ * sizeof(float), hipMemcpyDeviceToDevice, stream);

  cvt_k<<<2048, 256, 0, stream>>>(x, s0, (int)(SLOT/8), 1.0f);
  cvt_w_k<<<1152, 256, 0, stream>>>(Wq, Wk, Wv, Wo, wb);

  proj_k<<<dim3(128, 3, 3), 512, 0, stream>>>(s0, wb, bq, bk, bv, s1, s2, vtt);
  logits_k<<<dim3(2, 2, 48), 512, 0, stream>>>(s1, s2, P0, P1, P2, P3);
  softmax4_k<<<H_ * C_, 256, 0, stream>>>(P0, P1, P2, P3, probs, s2);
  ctx_k<<<dim3(2, 16, 12), 512, 0, stream>>>(s2, vtt, s1);
  oproj_k<<<dim3(128, 3), 512, 0, stream>>>(s1, wb + 3*589824, bo, out);
}